// Round 13
// baseline (438.402 us; speedup 1.0000x reference)
//
#include <hip/hip_runtime.h>
#include <hip/hip_bf16.h>
#include <math.h>

// Problem constants
#define BB 2
#define TT 2048
#define CC 1024
#define HH 16
#define DD 64
#define CHALF 512
#define NN (BB * TT)   // 4096 rows
#define LOG2E 1.44269504088896340736f

typedef __attribute__((ext_vector_type(8))) short short8;
typedef __attribute__((ext_vector_type(4))) short short4_t;
typedef __attribute__((ext_vector_type(4))) float f32x4;

__device__ __forceinline__ float gelu_exact(float x) {
    return 0.5f * x * (1.0f + erff(x * 0.70710678118654752f));
}

__device__ __forceinline__ short f2bf(float f) {
    __hip_bfloat16 h = __float2bfloat16(f);
    short s;
    __builtin_memcpy(&s, &h, 2);
    return s;
}

__device__ __forceinline__ float bf2f(short s) {
    __hip_bfloat16 h;
    __builtin_memcpy(&h, &s, 2);
    return __bfloat162float(h);
}

__device__ __forceinline__ short4_t pack_bf16x4(float a, float b, float c,
                                                float d) {
    short4_t s4;
    s4[0] = f2bf(a);
    s4[1] = f2bf(b);
    s4[2] = f2bf(c);
    s4[3] = f2bf(d);
    return s4;
}

// async global->LDS, 16 B per lane; LDS dst must be wave-uniform base
__device__ __forceinline__ void async_copy16(const void* g, void* l) {
    __builtin_amdgcn_global_load_lds(
        (const __attribute__((address_space(1))) void*)g,
        (__attribute__((address_space(3))) void*)l, 16, 0, 0);
}

// ---------------------------------------------------------------------------
// prep: x->bf16, mask tile flags, 5 weight transposes + imp_w1 transpose +
// plain bf16 convert of rsn_w2 (row-major, for the W_qc fusion GEMM).
// blocks: [0,2048) x conv; [2048,4096) mask; [4096,4224) imp_w1;
//         [4224,5504) 5 transposes; [5504,6016) rsn_w2 plain convert
// ---------------------------------------------------------------------------
__global__ __launch_bounds__(256) void prep(
    const float* __restrict__ x, __hip_bfloat16* __restrict__ x_bf,
    const int* __restrict__ mask, int* __restrict__ flags,
    const float* w0, const float* w1, const float* w2, const float* w3,
    const float* w4, const float* w5, const float* w6,
    __hip_bfloat16* t0, __hip_bfloat16* t1, __hip_bfloat16* t2,
    __hip_bfloat16* t3, __hip_bfloat16* t4, __hip_bfloat16* t5,
    __hip_bfloat16* t6) {
    __shared__ float T[64][65];
    int blk = blockIdx.x;
    int tid = threadIdx.x;
    if (blk < 2048) {
        int i = (blk * 256 + tid) * 8;
        float4 a = *(const float4*)&x[i];
        float4 b = *(const float4*)&x[i + 4];
        __hip_bfloat16 o[8] = {
            __float2bfloat16(a.x), __float2bfloat16(a.y),
            __float2bfloat16(a.z), __float2bfloat16(a.w),
            __float2bfloat16(b.x), __float2bfloat16(b.y),
            __float2bfloat16(b.z), __float2bfloat16(b.w)};
        *(float4*)&x_bf[i] = *(float4*)o;
    } else if (blk < 4096) {
        int idx = blk - 2048;
        int kt = idx & 31, qt = (idx >> 5) & 31, b = idx >> 10;
        int* red = (int*)T;
        int r = tid >> 2;
        int c0 = (tid & 3) * 16;
        const int* base =
            mask + ((size_t)(b * TT + qt * 64 + r)) * TT + kt * 64 + c0;
        int all = 1;
#pragma unroll
        for (int i = 0; i < 4; ++i) {
            int4 m4 = *(const int4*)(base + i * 4);
            all &= (m4.x != 0) & (m4.y != 0) & (m4.z != 0) & (m4.w != 0);
        }
        red[tid] = all;
        __syncthreads();
#pragma unroll
        for (int o = 128; o > 0; o >>= 1) {
            if (tid < o) red[tid] &= red[tid + o];
            __syncthreads();
        }
        if (tid == 0) flags[(b * 32 + qt) * 32 + kt] = red[0];
    } else {
        int idx = blk - 4096;
        if (idx >= 1408) {
            // plain bf16 convert of rsn_w2 (row-major), 2048 elems/block
            int i = (idx - 1408) * 2048 + tid * 8;
            float4 a = *(const float4*)&w2[i];
            float4 b = *(const float4*)&w2[i + 4];
            __hip_bfloat16 o[8] = {
                __float2bfloat16(a.x), __float2bfloat16(a.y),
                __float2bfloat16(a.z), __float2bfloat16(a.w),
                __float2bfloat16(b.x), __float2bfloat16(b.y),
                __float2bfloat16(b.z), __float2bfloat16(b.w)};
            *(float4*)&t2[i] = *(float4*)o;
            return;
        }
        const float* W;
        __hip_bfloat16* Wt;
        int N = 1024, n0, k0;
        if (idx < 128) {
            W = w0; Wt = t0; N = 512;
            n0 = (idx & 7) * 64;
            k0 = (idx >> 3) * 64;
        } else {
            idx -= 128;
            int w = idx >> 8;
            int r = idx & 255;
            n0 = (r & 15) * 64;
            k0 = (r >> 4) * 64;
            switch (w) {
                case 0: W = w1; Wt = t1; break;   // rsn_w1
                case 1: W = w3; Wt = t3; break;   // q_w
                case 2: W = w4; Wt = t4; break;   // k_w
                case 3: W = w5; Wt = t5; break;   // v_w
                default: W = w6; Wt = t6; break;  // o_w
            }
        }
        int c = tid & 63, r4 = tid >> 6;
#pragma unroll
        for (int i = 0; i < 16; ++i) {
            int row = i * 4 + r4;
            T[row][c] = W[(size_t)(k0 + row) * N + n0 + c];
        }
        __syncthreads();
#pragma unroll
        for (int i = 0; i < 16; ++i) {
            int row = i * 4 + r4;  // n index
            Wt[(size_t)(n0 + row) * CC + k0 + c] = __float2bfloat16(T[c][row]);
        }
    }
}

// ---------------------------------------------------------------------------
// bf16 MFMA GEMM, 64x128 tile, BK=64 (16 MFMA/barrier): C = A @ Wt^T + bias
// ---------------------------------------------------------------------------
template <bool BF16OUT>
__global__ __launch_bounds__(256) void gemm_mfma64(
    const short* __restrict__ A, const short* __restrict__ Wt,
    const float* __restrict__ bias, float* __restrict__ Cf,
    __hip_bfloat16* __restrict__ Cb, int M, int N, int K) {
    __shared__ short As0[64][32], As1[64][32];
    __shared__ short Bs0[128][32], Bs1[128][32];
    int tid = threadIdx.x;
    int wave = tid >> 6, lane = tid & 63;
    int m16 = lane & 15, quad = lane >> 4;
    int wm = wave >> 1, wn = wave & 1;
    int row0 = blockIdx.y * 64, col0 = blockIdx.x * 128;
    int lr = lane >> 2;        // 0..15
    int kof = (lane & 3) * 8;

    f32x4 acc[2][4];
#pragma unroll
    for (int i = 0; i < 2; ++i)
#pragma unroll
        for (int j = 0; j < 4; ++j) acc[i][j] = (f32x4){0.f, 0.f, 0.f, 0.f};

    for (int k0 = 0; k0 < K; k0 += 64) {
        const short* arow = A + (size_t)(row0 + wave * 16 + lr) * K + k0 + kof;
        async_copy16(arow, &As0[wave * 16][0]);
        async_copy16(arow + 32, &As1[wave * 16][0]);
#pragma unroll
        for (int j = 0; j < 2; ++j) {
            int rbase = wave * 32 + j * 16;
            const short* brow =
                Wt + (size_t)(col0 + rbase + lr) * K + k0 + kof;
            async_copy16(brow, &Bs0[rbase][0]);
            async_copy16(brow + 32, &Bs1[rbase][0]);
        }
        __syncthreads();
#pragma unroll
        for (int kc = 0; kc < 2; ++kc) {
            short8 af[2], bfr[4];
#pragma unroll
            for (int i = 0; i < 2; ++i)
                af[i] = kc ? *(const short8*)&As1[wm * 32 + i * 16 + m16][quad * 8]
                           : *(const short8*)&As0[wm * 32 + i * 16 + m16][quad * 8];
#pragma unroll
            for (int j = 0; j < 4; ++j)
                bfr[j] = kc ? *(const short8*)&Bs1[wn * 64 + j * 16 + m16][quad * 8]
                            : *(const short8*)&Bs0[wn * 64 + j * 16 + m16][quad * 8];
#pragma unroll
            for (int i = 0; i < 2; ++i)
#pragma unroll
                for (int j = 0; j < 4; ++j)
                    acc[i][j] = __builtin_amdgcn_mfma_f32_16x16x32_bf16(
                        af[i], bfr[j], acc[i][j], 0, 0, 0);
        }
        __syncthreads();
    }
#pragma unroll
    for (int i = 0; i < 2; ++i) {
#pragma unroll
        for (int j = 0; j < 4; ++j) {
            int col = col0 + wn * 64 + j * 16 + m16;
            float bv = bias[col];
#pragma unroll
            for (int rr = 0; rr < 4; ++rr) {
                int row = row0 + wm * 32 + i * 16 + quad * 4 + rr;
                float val = acc[i][j][rr] + bv;
                if (BF16OUT)
                    Cb[(size_t)row * N + col] = __float2bfloat16(val);
                else
                    Cf[(size_t)row * N + col] = val;
            }
        }
    }
}

// ---------------------------------------------------------------------------
// Batched q/k/v projections, 128x128 tile, BK=64.
// z=0: q = h2b @ W_qc (fused rsn_w2*q_w) + bias_qc, scaled by temp/8*log2e
// z=1: k = xi @ k_w; z=2: v = x @ v_w written TRANSPOSED (vt)
// ---------------------------------------------------------------------------
__global__ __launch_bounds__(256) void gemm_qkv(
    const short* __restrict__ Aq, const short* __restrict__ Ak,
    const short* __restrict__ Av, const short* __restrict__ Wq,
    const short* __restrict__ Wk, const short* __restrict__ Wv,
    const float* __restrict__ bq, const float* __restrict__ bk,
    const float* __restrict__ bv, __hip_bfloat16* __restrict__ Cq,
    __hip_bfloat16* __restrict__ Ck, __hip_bfloat16* __restrict__ Cv,
    const float* __restrict__ tmp) {
    int z = blockIdx.z;
    const short* A = (z == 0) ? Aq : (z == 1) ? Ak : Av;
    const short* Wt = (z == 0) ? Wq : (z == 1) ? Wk : Wv;
    const float* bias = (z == 0) ? bq : (z == 1) ? bk : bv;

    __shared__ short As0[128][32], As1[128][32];
    __shared__ short Bs0[128][32], Bs1[128][32];
    int tid = threadIdx.x;
    int wave = tid >> 6, lane = tid & 63;
    int m16 = lane & 15, quad = lane >> 4;
    int wm = wave >> 1, wn = wave & 1;
    int row0 = blockIdx.y * 128, col0 = blockIdx.x * 128;
    int lr = lane >> 2;
    int kof = (lane & 3) * 8;

    float scale = 1.0f;
    if (z == 0)
        scale = tmp[(row0 >> 11) * HH + (col0 >> 6) + wn] * 0.125f * LOG2E;

    f32x4 acc[4][4];
#pragma unroll
    for (int i = 0; i < 4; ++i)
#pragma unroll
        for (int j = 0; j < 4; ++j) acc[i][j] = (f32x4){0.f, 0.f, 0.f, 0.f};

    for (int k0 = 0; k0 < CC; k0 += 64) {
#pragma unroll
        for (int j = 0; j < 2; ++j) {
            int rbase = wave * 32 + j * 16;
            const short* ar = A + (size_t)(row0 + rbase + lr) * CC + k0 + kof;
            async_copy16(ar, &As0[rbase][0]);
            async_copy16(ar + 32, &As1[rbase][0]);
            const short* br = Wt + (size_t)(col0 + rbase + lr) * CC + k0 + kof;
            async_copy16(br, &Bs0[rbase][0]);
            async_copy16(br + 32, &Bs1[rbase][0]);
        }
        __syncthreads();
#pragma unroll
        for (int kc = 0; kc < 2; ++kc) {
            short8 af[4], bfr[4];
#pragma unroll
            for (int i = 0; i < 4; ++i)
                af[i] = kc ? *(const short8*)&As1[wm * 64 + i * 16 + m16][quad * 8]
                           : *(const short8*)&As0[wm * 64 + i * 16 + m16][quad * 8];
#pragma unroll
            for (int j = 0; j < 4; ++j)
                bfr[j] = kc ? *(const short8*)&Bs1[wn * 64 + j * 16 + m16][quad * 8]
                            : *(const short8*)&Bs0[wn * 64 + j * 16 + m16][quad * 8];
#pragma unroll
            for (int i = 0; i < 4; ++i)
#pragma unroll
                for (int j = 0; j < 4; ++j)
                    acc[i][j] = __builtin_amdgcn_mfma_f32_16x16x32_bf16(
                        af[i], bfr[j], acc[i][j], 0, 0, 0);
        }
        __syncthreads();
    }
    if (z == 2) {
        int b = row0 >> 11;
        int t0r = (row0 & (TT - 1)) + wm * 64 + quad * 4;
#pragma unroll
        for (int i = 0; i < 4; ++i) {
#pragma unroll
            for (int j = 0; j < 4; ++j) {
                int col = col0 + wn * 64 + j * 16 + m16;
                int h = col >> 6, d = col & 63;
                float bv2 = bias[col];
                short4_t pk = pack_bf16x4(
                    acc[i][j][0] + bv2, acc[i][j][1] + bv2,
                    acc[i][j][2] + bv2, acc[i][j][3] + bv2);
                *(short4_t*)&Cv[(((size_t)(b * HH + h) * DD) + d) * TT + t0r +
                                i * 16] = pk;
            }
        }
    } else {
        __hip_bfloat16* C = (z == 0) ? Cq : Ck;
#pragma unroll
        for (int i = 0; i < 4; ++i) {
#pragma unroll
            for (int j = 0; j < 4; ++j) {
                int col = col0 + wn * 64 + j * 16 + m16;
                float bv2 = bias[col];
#pragma unroll
                for (int rr = 0; rr < 4; ++rr) {
                    int row = row0 + wm * 64 + i * 16 + quad * 4 + rr;
                    C[(size_t)row * CC + col] =
                        __float2bfloat16((acc[i][j][rr] + bv2) * scale);
                }
            }
        }
    }
}

// ---------------------------------------------------------------------------
// fused q bias: bias_qc[j] = q_wt[j][:] . rsn_b2 + q_b[j]
// ---------------------------------------------------------------------------
__global__ __launch_bounds__(256) void bias_qc_kernel(
    const short* __restrict__ q_wt, const float* __restrict__ rsn_b2,
    const float* __restrict__ q_b, float* __restrict__ bias_qc) {
    int j = blockIdx.x * 4 + (threadIdx.x >> 6);
    int lane = threadIdx.x & 63;
    const short* row = q_wt + (size_t)j * CC + lane * 16;
    short8 a0 = *(const short8*)row;
    short8 a1 = *(const short8*)(row + 8);
    float s = 0.f;
#pragma unroll
    for (int u = 0; u < 8; ++u) s = fmaf(bf2f(a0[u]), rsn_b2[lane * 16 + u], s);
#pragma unroll
    for (int u = 0; u < 8; ++u)
        s = fmaf(bf2f(a1[u]), rsn_b2[lane * 16 + 8 + u], s);
#pragma unroll
    for (int off = 1; off < 64; off <<= 1) s += __shfl_xor(s, off, 64);
    if (lane == 0) bias_qc[j] = s + q_b[j];
}

// ---------------------------------------------------------------------------
// fused importance epilogue: LN(h1)+GELU -> dot w2 -> sigmoid -> xi = x*imp
// ---------------------------------------------------------------------------
__global__ __launch_bounds__(256) void imp_fused(
    const float* __restrict__ h1, const float* __restrict__ g,
    const float* __restrict__ beta, const float* __restrict__ w2,
    const float* __restrict__ b2, const float* __restrict__ x,
    __hip_bfloat16* __restrict__ xi) {
    int row = blockIdx.x;
    int tid = threadIdx.x;
    const float* hr = h1 + (size_t)row * CHALF;
    float v0 = hr[tid], v1 = hr[tid + 256];
    __shared__ float red[256];
    red[tid] = v0 + v1;
    __syncthreads();
#pragma unroll
    for (int o = 128; o > 0; o >>= 1) {
        if (tid < o) red[tid] += red[tid + o];
        __syncthreads();
    }
    float mean = red[0] * (1.0f / CHALF);
    __syncthreads();
    float d0 = v0 - mean, d1 = v1 - mean;
    red[tid] = d0 * d0 + d1 * d1;
    __syncthreads();
#pragma unroll
    for (int o = 128; o > 0; o >>= 1) {
        if (tid < o) red[tid] += red[tid + o];
        __syncthreads();
    }
    float inv = rsqrtf(red[0] * (1.0f / CHALF) + 1e-5f);
    __syncthreads();
    float ge0 = gelu_exact(d0 * inv * g[tid] + beta[tid]);
    float ge1 = gelu_exact(d1 * inv * g[tid + 256] + beta[tid + 256]);
    red[tid] = ge0 * w2[tid] + ge1 * w2[tid + 256];
    __syncthreads();
#pragma unroll
    for (int o = 128; o > 0; o >>= 1) {
        if (tid < o) red[tid] += red[tid + o];
        __syncthreads();
    }
    float z = red[0] + b2[0];
    float sg = 1.0f / (1.0f + expf(-z));
    float imp = fmaxf(sg, 1e-6f);
#pragma unroll
    for (int i = 0; i < 4; ++i) {
        int c = i * 256 + tid;
        xi[(size_t)row * CC + c] =
            __float2bfloat16(x[(size_t)row * CC + c] * imp);
    }
}

// ---------------------------------------------------------------------------
// LN + GELU, bf16 in -> bf16 out (vectorized short4 per thread)
// ---------------------------------------------------------------------------
__global__ __launch_bounds__(256) void ln_gelu_bb(
    const __hip_bfloat16* __restrict__ Y, const float* __restrict__ g,
    const float* __restrict__ beta, __hip_bfloat16* __restrict__ O) {
    int row = blockIdx.x;
    int tid = threadIdx.x;
    int c0 = tid * 4;
    short4_t raw = *(const short4_t*)&Y[(size_t)row * CC + c0];
    float v[4];
    float s = 0.f;
#pragma unroll
    for (int i = 0; i < 4; ++i) {
        v[i] = bf2f(raw[i]);
        s += v[i];
    }
    __shared__ float red[256];
    red[tid] = s;
    __syncthreads();
#pragma unroll
    for (int o = 128; o > 0; o >>= 1) {
        if (tid < o) red[tid] += red[tid + o];
        __syncthreads();
    }
    float mean = red[0] * (1.0f / CC);
    __syncthreads();
    s = 0.f;
#pragma unroll
    for (int i = 0; i < 4; ++i) {
        float d = v[i] - mean;
        s += d * d;
    }
    red[tid] = s;
    __syncthreads();
#pragma unroll
    for (int o = 128; o > 0; o >>= 1) {
        if (tid < o) red[tid] += red[tid + o];
        __syncthreads();
    }
    float inv = rsqrtf(red[0] * (1.0f / CC) + 1e-5f);
    float4 gg = *(const float4*)&g[c0];
    float4 bb = *(const float4*)&beta[c0];
    short4_t ov = pack_bf16x4(
        gelu_exact((v[0] - mean) * inv * gg.x + bb.x),
        gelu_exact((v[1] - mean) * inv * gg.y + bb.y),
        gelu_exact((v[2] - mean) * inv * gg.z + bb.z),
        gelu_exact((v[3] - mean) * inv * gg.w + bb.w));
    *(short4_t*)&O[(size_t)row * CC + c0] = ov;
}

// ---------------------------------------------------------------------------
// mean over T (stage 1): partials over 128-row chunks of h2b
// ---------------------------------------------------------------------------
__global__ __launch_bounds__(256) void mean_part(
    const __hip_bfloat16* __restrict__ R, float* __restrict__ part) {
    int idx = blockIdx.x * 256 + threadIdx.x;
    int c = idx & (CC - 1);
    int chunk = (idx >> 10) & 15;
    int b = idx >> 14;
    const __hip_bfloat16* base = R + ((size_t)(b * TT + chunk * 128)) * CC + c;
    float s = 0.f;
    for (int t = 0; t < 128; ++t) s += __bfloat162float(base[(size_t)t * CC]);
    part[idx] = s;
}

// ---------------------------------------------------------------------------
// rm = mean_T(h2b) @ rsn_w2 + rsn_b2  (mean linearity fusion)
// ---------------------------------------------------------------------------
__global__ __launch_bounds__(256) void rm_proj(
    const float* __restrict__ part, const short* __restrict__ rsn_w2r,
    const float* __restrict__ rsn_b2, float* __restrict__ rm) {
    __shared__ float mh[CC];
    __shared__ float red[256];
    int b = blockIdx.y;
    int c0 = blockIdx.x * 64;
    int tid = threadIdx.x;
    for (int cc = tid; cc < CC; cc += 256) {
        float s = 0.f;
#pragma unroll
        for (int ch = 0; ch < 16; ++ch)
            s += part[(size_t)(b * 16 + ch) * CC + cc];
        mh[cc] = s * (1.0f / TT);
    }
    __syncthreads();
    int col = c0 + (tid & 63);
    int kq = tid >> 6;
    float s = 0.f;
#pragma unroll 8
    for (int i = kq * 256; i < kq * 256 + 256; ++i)
        s = fmaf(mh[i], bf2f(rsn_w2r[(size_t)i * CC + col]), s);
    red[tid] = s;
    __syncthreads();
    if (tid < 64) {
        float t = red[tid] + red[tid + 64] + red[tid + 128] + red[tid + 192];
        rm[b * CC + c0 + tid] = t + rsn_b2[c0 + tid];
    }
}

// ---------------------------------------------------------------------------
// temp_net stage 1: acc1[b,col] = rm @ w1 + b1
// ---------------------------------------------------------------------------
__global__ __launch_bounds__(256) void temp_gemv1(
    const float* __restrict__ rm, const float* __restrict__ w1,
    const float* __restrict__ b1, float* __restrict__ acc1) {
    __shared__ float rm_l[CC];
    __shared__ float red[256];
    int b = blockIdx.y;
    int c0 = blockIdx.x * 64;
    int tid = threadIdx.x;
    for (int cc = tid; cc < CC; cc += 256) rm_l[cc] = rm[b * CC + cc];
    __syncthreads();
    int col = c0 + (tid & 63);
    int kq = tid >> 6;  // 0..3
    float s = 0.f;
#pragma unroll 8
    for (int i = kq * 256; i < kq * 256 + 256; ++i)
        s = fmaf(rm_l[i], w1[(size_t)i * CHALF + col], s);
    red[tid] = s;
    __syncthreads();
    if (tid < 64) {
        float t = red[tid] + red[tid + 64] + red[tid + 128] + red[tid + 192];
        acc1[b * CHALF + tid + c0] = t + b1[col];
    }
}

// ---------------------------------------------------------------------------
// temp_net stage 2: LN(acc1) -> GELU -> @w2 + b2 -> softplus + 0.5
// ---------------------------------------------------------------------------
__global__ __launch_bounds__(512) void temp_fin(
    const float* __restrict__ acc1, const float* __restrict__ g,
    const float* __restrict__ beta, const float* __restrict__ w2,
    const float* __restrict__ b2, float* __restrict__ temp) {
    __shared__ float red[512];
    __shared__ float wred[8][16];
    int b = blockIdx.x;
    int tid = threadIdx.x;
    int wave = tid >> 6, lane = tid & 63;
    float acc = acc1[b * CHALF + tid];
    red[tid] = acc;
    __syncthreads();
#pragma unroll
    for (int o = 256; o > 0; o >>= 1) {
        if (tid < o) red[tid] += red[tid + o];
        __syncthreads();
    }
    float mean = red[0] * (1.0f / CHALF);
    __syncthreads();
    float d = acc - mean;
    red[tid] = d * d;
    __syncthreads();
#pragma unroll
    for (int o = 256; o > 0; o >>= 1) {
        if (tid < o) red[tid] += red[tid + o];
        __syncthreads();
    }
    float inv = rsqrtf(red[0] * (1.0f / CHALF) + 1e-5f);
    float ht = gelu_exact((acc - mean) * inv * g[tid] + beta[tid]);
    float p[16];
#pragma unroll
    for (int j = 0; j < 16; ++j) p[j] = ht * w2[tid * HH + j];
#pragma unroll
    for (int off = 1; off < 64; off <<= 1)
#pragma unroll
        for (int j = 0; j < 16; ++j) p[j] += __shfl_xor(p[j], off, 64);
    if (lane == 0)
#pragma unroll
        for (int j = 0; j < 16; ++j) wred[wave][j] = p[j];
    __syncthreads();
    if (tid < HH) {
        float s = b2[tid];
#pragma unroll
        for (int w = 0; w < 8; ++w) s += wred[w][tid];
        float sp = fmaxf(s, 0.f) + log1pf(expf(-fabsf(s)));
        temp[b * HH + tid] = sp + 0.5f;
    }
}

// ---------------------------------------------------------------------------
// MFMA flash attention (R11 shape): 128-row q-tile, transposed-QK softmax,
// O^T PV (per-lane alpha/l), ballot-gated rescale, raw v_exp_f32.
// ---------------------------------------------------------------------------
__global__ __launch_bounds__(256) void flash_attn_mfma(
    const short* __restrict__ q, const short* __restrict__ k,
    const short* __restrict__ vt, const int* __restrict__ mask,
    const int* __restrict__ flags, __hip_bfloat16* __restrict__ out) {
    __shared__ short Ks[64][72];    // [key][d]
    __shared__ short Vt[64][72];    // [d][key]
    __shared__ short Ps[128][72];   // [q-row][key], wave-private strips
    int tid = threadIdx.x;
    int wave = tid >> 6, lane = tid & 63;
    int m16 = lane & 15, quad = lane >> 4;
    int qt = blockIdx.x;            // 128-row q tile
    int q0 = qt * 128;
    int bh = blockIdx.y;
    int b = bh >> 4, h = bh & 15;

    short8 qf[2][2];
#pragma unroll
    for (int qg = 0; qg < 2; ++qg) {
        const short* qrow = q + ((size_t)(b * TT + q0 + wave * 32 + qg * 16 + m16)) * CC +
                            h * DD + quad * 8;
        qf[qg][0] = *(const short8*)(qrow);
        qf[qg][1] = *(const short8*)(qrow + 32);
    }

    float m_run[2] = {-INFINITY, -INFINITY};
    float l_run[2] = {0.f, 0.f};
    f32x4 acc_o[2][4];
#pragma unroll
    for (int qg = 0; qg < 2; ++qg)
#pragma unroll
        for (int t = 0; t < 4; ++t) acc_o[qg][t] = (f32x4){0.f, 0.f, 0.f, 0.f};

    for (int kt = 0; kt < TT / 64; ++kt) {
        int kb = kt * 64;
#pragma unroll
        for (int i = 0; i < 2; ++i) {
            int idx = i * 256 + tid;
            int r = idx >> 3;
            int dc = (idx & 7) * 8;
            *(short8*)&Ks[r][dc] =
                *(const short8*)(k + ((size_t)(b * TT + kb + r)) * CC + h * DD + dc);
            *(short8*)&Vt[r][dc] =
                *(const short8*)(vt + ((size_t)bh * DD + r) * TT + kb + dc);
        }
        __syncthreads();

        short8 kf[4][2];
#pragma unroll
        for (int t = 0; t < 4; ++t) {
            kf[t][0] = *(const short8*)&Ks[t * 16 + m16][quad * 8];
            kf[t][1] = *(const short8*)&Ks[t * 16 + m16][32 + quad * 8];
        }
        int fl = flags[(b * 32 + 2 * qt + (wave >> 1)) * 32 + kt];

#pragma unroll
        for (int qg = 0; qg < 2; ++qg) {
            f32x4 sacc[4];
#pragma unroll
            for (int t = 0; t < 4; ++t) sacc[t] = (f32x4){0.f, 0.f, 0.f, 0.f};
#pragma unroll
            for (int t = 0; t < 4; ++t) {
                sacc[t] = __builtin_amdgcn_mfma_f32_16x16x32_bf16(kf[t][0], qf[qg][0], sacc[t], 0, 0, 0);
                sacc[t] = __builtin_amdgcn_mfma_f32_16x16x32_bf16(kf[t][1], qf[qg][1], sacc[t], 0, 0, 0);
            }
            float sv[4][4];
#pragma unroll
            for (int t = 0; t < 4; ++t)
#pragma unroll
                for (int r = 0; r < 4; ++r) sv[t][r] = sacc[t][r];
            if (fl == 0) {
                int qrow = q0 + wave * 32 + qg * 16 + m16;
#pragma unroll
                for (int t = 0; t < 4; ++t)
#pragma unroll
                    for (int r = 0; r < 4; ++r) {
                        int kg = kb + t * 16 + quad * 4 + r;
                        if (mask[((size_t)(b * TT + qrow)) * TT + kg] == 0)
                            sv[t][r] = -INFINITY;
                    }
            }
            float mx = sv[0][0];
#pragma unroll
            for (int t = 0; t < 4; ++t)
#pragma unroll
                for (int r = 0; r < 4; ++r) mx = fmaxf(mx, sv[t][r]);
            mx = fmaxf(mx, __shfl_xor(mx, 16, 64));
            mx = fmaxf(mx, __shfl_xor(mx, 32, 64));
            float mnew = fmaxf(m_run[qg], mx);
            if (__any(mnew > m_run[qg])) {
                float alpha = __builtin_amdgcn_exp2f(m_run[qg] - mnew);
                l_run[qg] *= alpha;
#pragma unroll
                for (int td = 0; td < 4; ++td)
#pragma unroll
                    for (int r = 0; r < 4; ++r) acc_o[qg][td][r] *= alpha;
            }
            m_run[qg] = mnew;
            int prow = wave * 32 + qg * 16 + m16;
            float psum = 0.f;
#pragma unroll
            for (int t = 0; t < 4; ++t) {
                short4_t pk;
#pragma unroll
                for (int r = 0; r < 4; ++r) {
                    float p = __builtin_amdgcn_exp2f(sv[t][r] - mnew);
                    psum += p;
                    pk[r] = f2bf(p);
                }
                *(short4_t*)&Ps[prow][t * 16 + quad * 4] = pk;
            }
            psum += __shfl_xor(psum, 16, 64);
            psum += __shfl_xor(psum, 32, 64);
            l_run[qg] += psum;
        }

        // PV as O^T = V^T P^T
#pragma unroll
        for (int kc = 0; kc < 2; ++kc) {
            short8 vf[4];
#pragma unroll
            for (int td = 0; td < 4; ++td)
                vf[td] = *(const short8*)&Vt[td * 16 + m16][kc * 32 + quad * 8];
#pragma unroll
            for (int qg = 0; qg < 2; ++qg) {
                short8 pf = *(const short8*)&Ps[wave * 32 + qg * 16 + m16][kc * 32 + quad * 8];
#pragma unroll
                for (int td = 0; td < 4; ++td)
                    acc_o[qg][td] = __builtin_amdgcn_mfma_f32_16x16x32_bf16(
                        vf[td], pf, acc_o[qg][td], 0, 0, 0);
            }
        }
        __syncthreads();
    }

#pragma unroll
    for (int qg = 0; qg < 2; ++qg) {
        float inv = 1.0f / l_run[qg];
        int row = b * TT + q0 + wave * 32 + qg * 16 + m16;
#pragma unroll
        for (int td = 0; td < 4; ++td) {
            short4_t pk = pack_bf16x4(
                acc_o[qg][td][0] * inv, acc_o[qg][td][1] * inv,
                acc_o[qg][td][2] * inv, acc_o[qg][td][3] * inv);
            *(short4_t*)&out[(size_t)row * CC + h * DD + td * 16 + quad * 4] = pk;
        }
    }
}

// ---------------------------------------------------------------------------
// Final: out = LN(x + proj), proj in bf16 (vectorized 4/thread)
// ---------------------------------------------------------------------------
__global__ __launch_bounds__(256) void final_ln_b(
    const float* __restrict__ x, const __hip_bfloat16* __restrict__ p,
    const float* __restrict__ g, const float* __restrict__ beta,
    float* __restrict__ out) {
    int row = blockIdx.x;
    int tid = threadIdx.x;
    int c0 = tid * 4;
    float4 xv = *(const float4*)&x[(size_t)row * CC + c0];
    short4_t pv = *(const short4_t*)&p[(size_t)row * CC + c0];
    float v[4] = {xv.x + bf2f(pv[0]), xv.y + bf2f(pv[1]),
                  xv.z + bf2f(pv[2]), xv.w + bf2f(pv[3])};
    float s = v[0] + v[1] + v[2] + v[3];
    __shared__ float red[256];
    red[tid] = s;
    __syncthreads();
#pragma unroll
    for (int o = 128; o > 0; o >>= 1) {
        if (tid < o) red[tid] += red[tid + o];
        __syncthreads();
    }
    float mean = red[0] * (1.0f / CC);
    __syncthreads();
    s = 0.f;
#pragma unroll
    for (int i = 0; i < 4; ++i) {
        float d = v[i] - mean;
        s += d * d;
    }
    red[tid] = s;
    __syncthreads();
#pragma unroll
    for (int o = 128; o > 0; o >>= 1) {
        if (tid < o) red[tid] += red[tid + o];
        __syncthreads();
    }
    float inv = rsqrtf(red[0] * (1.0f / CC) + 1e-5f);
    float4 gg = *(const float4*)&g[c0];
    float4 bb = *(const float4*)&beta[c0];
    float4 ov = {(v[0] - mean) * inv * gg.x + bb.x,
                 (v[1] - mean) * inv * gg.y + bb.y,
                 (v[2] - mean) * inv * gg.z + bb.z,
                 (v[3] - mean) * inv * gg.w + bb.w};
    *(float4*)&out[(size_t)row * CC + c0] = ov;
}

extern "C" void kernel_launch(void* const* d_in, const int* in_sizes, int n_in,
                              void* d_out, int out_size, void* d_ws,
                              size_t ws_size, hipStream_t stream) {
    const float* x        = (const float*)d_in[0];
    const int*   mask     = (const int*)d_in[1];
    const float* imp_w1   = (const float*)d_in[2];
    const float* imp_b1   = (const float*)d_in[3];
    const float* imp_g    = (const float*)d_in[4];
    const float* imp_beta = (const float*)d_in[5];
    const float* imp_w2   = (const float*)d_in[6];
    const float* imp_b2   = (const float*)d_in[7];
    const float* rsn_w1   = (const float*)d_in[8];
    const float* rsn_b1   = (const float*)d_in[9];
    const float* rsn_g    = (const float*)d_in[10];
    const float* rsn_beta = (const float*)d_in[11];
    const float* rsn_w2   = (const float*)d_in[12];
    const float* rsn_b2   = (const float*)d_in[13];
    const float* q_w      = (const float*)d_in[14];
    const float* q_b      = (const float*)d_in[15];
    const float* k_w      = (const float*)d_in[16];
    const float* k_b      = (const float*)d_in[17];
    const float* v_w      = (const float*)d_in[18];
    const float* v_b      = (const float*)d_in[19];
    const float* o_w      = (const float*)d_in[20];
    const float* o_b      = (const float*)d_in[21];
    const float* tmp_w1   = (const float*)d_in[22];
    const float* tmp_b1   = (const float*)d_in[23];
    const float* tmp_g    = (const float*)d_in[24];
    const float* tmp_beta = (const float*)d_in[25];
    const float* tmp_w2   = (const float*)d_in[26];
    const float* tmp_b2   = (const float*)d_in[27];
    const float* norm_g   = (const float*)d_in[28];
    const float* norm_b   = (const float*)d_in[29];
    float* out = (float*)d_out;
    float* ws  = (float*)d_ws;

    // workspace layout (float offsets)
    float* h1  = ws;                       // [4096,512] fp32
    __hip_bfloat16* g1b   = (__hip_bfloat16*)(ws + 2097152);   // rsn1 out (later o-proj out)
    __hip_bfloat16* x_bf  = (__hip_bfloat16*)(ws + 6291456);
    __hip_bfloat16* xi_bf = (__hip_bfloat16*)(ws + 8388608);
    __hip_bfloat16* h2b   = (__hip_bfloat16*)(ws + 10485760);  // LN(rsn1) out
    __hip_bfloat16* rs_bf = (__hip_bfloat16*)(ws + 12582912);  // flash out (8 MB)
    __hip_bfloat16* w_qct = rs_bf;          // fused q-weight (2 MB), dead before flash
    __hip_bfloat16* qb    = (__hip_bfloat16*)(ws + 14680064);
    __hip_bfloat16* rsn_w2r = qb;           // plain-converted rsn_w2 (2 MB), dead before qkv
    __hip_bfloat16* kb    = (__hip_bfloat16*)(ws + 16777216);
    __hip_bfloat16* vtb   = (__hip_bfloat16*)(ws + 20971520);  // [32,64,2048]
    __hip_bfloat16* imp_w1t = (__hip_bfloat16*)(ws + 23068672);  // [512,1024]
    __hip_bfloat16* rsn_w1t = (__hip_bfloat16*)(ws + 23330816);  // [1024,1024]
    __hip_bfloat16* q_wt    = (__hip_bfloat16*)(ws + 24379392);
    __hip_bfloat16* k_wt    = (__hip_bfloat16*)(ws + 24903680);
    __hip_bfloat16* v_wt    = (__hip_bfloat16*)(ws + 25427968);
    __hip_bfloat16* o_wt    = (__hip_bfloat16*)(ws + 25952256);
    float* tmp  = ws + 26478592;   // [2,16]
    float* part = ws + 26479104;   // [2,16,1024]
    int*   flg  = (int*)(ws + 26511872);  // [2,32,32]
    float* acc1 = ws + 26513920;   // [2,512]
    float* zeros   = ws + 26514944;  // [1024]
    float* bias_qc = ws + 26515968;  // [1024]
    float* rm      = ws + 26516992;  // [2,1024]

    dim3 blk(256);
    hipMemsetAsync(zeros, 0, 1024 * sizeof(float), stream);
    // fused prep: x->bf16, mask flags, weight transposes + rsn_w2 plain conv
    prep<<<6016, blk, 0, stream>>>(
        x, x_bf, mask, flg,
        imp_w1, rsn_w1, rsn_w2, q_w, k_w, v_w, o_w,
        imp_w1t, rsn_w1t, rsn_w2r, q_wt, k_wt, v_wt, o_wt);
    // W_qc = rsn_w2 @ q_w, stored transposed ([j][i]) for the q projection
    gemm_mfma64<true><<<dim3(CC / 128, 1024 / 64), blk, 0, stream>>>(
        (const short*)q_wt, (const short*)rsn_w2r, zeros, nullptr, w_qct,
        1024, CC, CC);
    // fused q bias: rsn_b2 @ q_w + q_b
    bias_qc_kernel<<<256, blk, 0, stream>>>((const short*)q_wt, rsn_b2, q_b,
                                            bias_qc);
    // importance net (GEMM + fused LN/GELU/gate)
    gemm_mfma64<false><<<dim3(CHALF / 128, NN / 64), blk, 0, stream>>>(
        (const short*)x_bf, (const short*)imp_w1t, imp_b1, h1, nullptr, NN, CHALF, CC);
    imp_fused<<<NN, blk, 0, stream>>>(h1, imp_g, imp_beta, imp_w2, imp_b2, x, xi_bf);
    // reasoning net stage 1 (rsn2 is folded into q via W_qc)
    gemm_mfma64<true><<<dim3(CC / 128, NN / 64), blk, 0, stream>>>(
        (const short*)xi_bf, (const short*)rsn_w1t, rsn_b1, nullptr, g1b, NN, CC, CC);
    ln_gelu_bb<<<NN, blk, 0, stream>>>(g1b, rsn_g, rsn_beta, h2b);
    // temperature net: mean(h2b) -> @rsn_w2 + b2 -> temp MLP
    mean_part<<<128, blk, 0, stream>>>(h2b, part);
    rm_proj<<<dim3(CC / 64, BB), blk, 0, stream>>>(part, (const short*)rsn_w2r,
                                                   rsn_b2, rm);
    temp_gemv1<<<dim3(CHALF / 64, BB), blk, 0, stream>>>(rm, tmp_w1, tmp_b1, acc1);
    temp_fin<<<BB, dim3(512), 0, stream>>>(acc1, tmp_g, tmp_beta, tmp_w2, tmp_b2, tmp);
    // q/k/v projections batched; q = h2b @ W_qc (temp/8*log2e folded)
    gemm_qkv<<<dim3(CC / 128, NN / 128, 3), blk, 0, stream>>>(
        (const short*)h2b, (const short*)xi_bf, (const short*)x_bf,
        (const short*)w_qct, (const short*)k_wt, (const short*)v_wt,
        bias_qc, k_b, v_b, qb, kb, vtb, tmp);
    // flash attention (R11 config, measured-best)
    flash_attn_mfma<<<dim3(TT / 128, BB * HH), blk, 0, stream>>>(
        (const short*)qb, (const short*)kb, (const short*)vtb, mask, flg, rs_bf);
    // output projection + residual LN
    gemm_mfma64<true><<<dim3(CC / 128, NN / 64), blk, 0, stream>>>(
        (const short*)rs_bf, (const short*)o_wt, o_b, nullptr, g1b, NN, CC, CC);
    final_ln_b<<<NN, blk, 0, stream>>>(x, g1b, norm_g, norm_b, out);
}

// Round 14
// 411.639 us; speedup vs baseline: 1.0650x; 1.0650x over previous
//
#include <hip/hip_runtime.h>
#include <hip/hip_bf16.h>
#include <math.h>

// Problem constants
#define BB 2
#define TT 2048
#define CC 1024
#define HH 16
#define DD 64
#define CHALF 512
#define NN (BB * TT)   // 4096 rows
#define LOG2E 1.44269504088896340736f

typedef __attribute__((ext_vector_type(8))) short short8;
typedef __attribute__((ext_vector_type(4))) short short4_t;
typedef __attribute__((ext_vector_type(4))) float f32x4;

__device__ __forceinline__ float gelu_exact(float x) {
    return 0.5f * x * (1.0f + erff(x * 0.70710678118654752f));
}

__device__ __forceinline__ short f2bf(float f) {
    __hip_bfloat16 h = __float2bfloat16(f);
    short s;
    __builtin_memcpy(&s, &h, 2);
    return s;
}

__device__ __forceinline__ float bf2f(short s) {
    __hip_bfloat16 h;
    __builtin_memcpy(&h, &s, 2);
    return __bfloat162float(h);
}

__device__ __forceinline__ short4_t pack_bf16x4(float a, float b, float c,
                                                float d) {
    short4_t s4;
    s4[0] = f2bf(a);
    s4[1] = f2bf(b);
    s4[2] = f2bf(c);
    s4[3] = f2bf(d);
    return s4;
}

// async global->LDS, 16 B per lane; LDS dst must be wave-uniform base
__device__ __forceinline__ void async_copy16(const void* g, void* l) {
    __builtin_amdgcn_global_load_lds(
        (const __attribute__((address_space(1))) void*)g,
        (__attribute__((address_space(3))) void*)l, 16, 0, 0);
}

// ---------------------------------------------------------------------------
// prep: one launch for x->bf16 convert, mask tile flags, 7 weight transposes.
// ---------------------------------------------------------------------------
__global__ __launch_bounds__(256) void prep(
    const float* __restrict__ x, __hip_bfloat16* __restrict__ x_bf,
    const int* __restrict__ mask, int* __restrict__ flags,
    const float* w0, const float* w1, const float* w2, const float* w3,
    const float* w4, const float* w5, const float* w6,
    __hip_bfloat16* t0, __hip_bfloat16* t1, __hip_bfloat16* t2,
    __hip_bfloat16* t3, __hip_bfloat16* t4, __hip_bfloat16* t5,
    __hip_bfloat16* t6) {
    __shared__ float T[64][65];
    int blk = blockIdx.x;
    int tid = threadIdx.x;
    if (blk < 2048) {
        int i = (blk * 256 + tid) * 8;
        float4 a = *(const float4*)&x[i];
        float4 b = *(const float4*)&x[i + 4];
        __hip_bfloat16 o[8] = {
            __float2bfloat16(a.x), __float2bfloat16(a.y),
            __float2bfloat16(a.z), __float2bfloat16(a.w),
            __float2bfloat16(b.x), __float2bfloat16(b.y),
            __float2bfloat16(b.z), __float2bfloat16(b.w)};
        *(float4*)&x_bf[i] = *(float4*)o;
    } else if (blk < 4096) {
        int idx = blk - 2048;
        int kt = idx & 31, qt = (idx >> 5) & 31, b = idx >> 10;
        int* red = (int*)T;
        int r = tid >> 2;
        int c0 = (tid & 3) * 16;
        const int* base =
            mask + ((size_t)(b * TT + qt * 64 + r)) * TT + kt * 64 + c0;
        int all = 1;
#pragma unroll
        for (int i = 0; i < 4; ++i) {
            int4 m4 = *(const int4*)(base + i * 4);
            all &= (m4.x != 0) & (m4.y != 0) & (m4.z != 0) & (m4.w != 0);
        }
        red[tid] = all;
        __syncthreads();
#pragma unroll
        for (int o = 128; o > 0; o >>= 1) {
            if (tid < o) red[tid] &= red[tid + o];
            __syncthreads();
        }
        if (tid == 0) flags[(b * 32 + qt) * 32 + kt] = red[0];
    } else {
        int idx = blk - 4096;
        const float* W;
        __hip_bfloat16* Wt;
        int N, n0, k0;
        if (idx < 128) {
            W = w0; Wt = t0; N = 512;
            n0 = (idx & 7) * 64;
            k0 = (idx >> 3) * 64;
        } else {
            idx -= 128;
            int w = idx >> 8;
            int r = idx & 255;
            N = 1024;
            n0 = (r & 15) * 64;
            k0 = (r >> 4) * 64;
            switch (w) {
                case 0: W = w1; Wt = t1; break;
                case 1: W = w2; Wt = t2; break;
                case 2: W = w3; Wt = t3; break;
                case 3: W = w4; Wt = t4; break;
                case 4: W = w5; Wt = t5; break;
                default: W = w6; Wt = t6; break;
            }
        }
        int c = tid & 63, r4 = tid >> 6;
#pragma unroll
        for (int i = 0; i < 16; ++i) {
            int row = i * 4 + r4;
            T[row][c] = W[(size_t)(k0 + row) * N + n0 + c];
        }
        __syncthreads();
#pragma unroll
        for (int i = 0; i < 16; ++i) {
            int row = i * 4 + r4;  // n index
            Wt[(size_t)(n0 + row) * CC + k0 + c] = __float2bfloat16(T[c][row]);
        }
    }
}

// ---------------------------------------------------------------------------
// bf16 MFMA GEMM, 64x128 tile, BK=64 (16 MFMA/barrier): C = A @ Wt^T + bias
// ---------------------------------------------------------------------------
template <bool BF16OUT>
__global__ __launch_bounds__(256) void gemm_mfma64(
    const short* __restrict__ A, const short* __restrict__ Wt,
    const float* __restrict__ bias, float* __restrict__ Cf,
    __hip_bfloat16* __restrict__ Cb, int M, int N, int K) {
    __shared__ short As0[64][32], As1[64][32];
    __shared__ short Bs0[128][32], Bs1[128][32];
    int tid = threadIdx.x;
    int wave = tid >> 6, lane = tid & 63;
    int m16 = lane & 15, quad = lane >> 4;
    int wm = wave >> 1, wn = wave & 1;
    int row0 = blockIdx.y * 64, col0 = blockIdx.x * 128;
    int lr = lane >> 2;        // 0..15
    int kof = (lane & 3) * 8;

    f32x4 acc[2][4];
#pragma unroll
    for (int i = 0; i < 2; ++i)
#pragma unroll
        for (int j = 0; j < 4; ++j) acc[i][j] = (f32x4){0.f, 0.f, 0.f, 0.f};

    for (int k0 = 0; k0 < K; k0 += 64) {
        const short* arow = A + (size_t)(row0 + wave * 16 + lr) * K + k0 + kof;
        async_copy16(arow, &As0[wave * 16][0]);
        async_copy16(arow + 32, &As1[wave * 16][0]);
#pragma unroll
        for (int j = 0; j < 2; ++j) {
            int rbase = wave * 32 + j * 16;
            const short* brow =
                Wt + (size_t)(col0 + rbase + lr) * K + k0 + kof;
            async_copy16(brow, &Bs0[rbase][0]);
            async_copy16(brow + 32, &Bs1[rbase][0]);
        }
        __syncthreads();
#pragma unroll
        for (int kc = 0; kc < 2; ++kc) {
            short8 af[2], bfr[4];
#pragma unroll
            for (int i = 0; i < 2; ++i)
                af[i] = kc ? *(const short8*)&As1[wm * 32 + i * 16 + m16][quad * 8]
                           : *(const short8*)&As0[wm * 32 + i * 16 + m16][quad * 8];
#pragma unroll
            for (int j = 0; j < 4; ++j)
                bfr[j] = kc ? *(const short8*)&Bs1[wn * 64 + j * 16 + m16][quad * 8]
                            : *(const short8*)&Bs0[wn * 64 + j * 16 + m16][quad * 8];
#pragma unroll
            for (int i = 0; i < 2; ++i)
#pragma unroll
                for (int j = 0; j < 4; ++j)
                    acc[i][j] = __builtin_amdgcn_mfma_f32_16x16x32_bf16(
                        af[i], bfr[j], acc[i][j], 0, 0, 0);
        }
        __syncthreads();
    }
#pragma unroll
    for (int i = 0; i < 2; ++i) {
#pragma unroll
        for (int j = 0; j < 4; ++j) {
            int col = col0 + wn * 64 + j * 16 + m16;
            float bv = bias[col];
#pragma unroll
            for (int rr = 0; rr < 4; ++rr) {
                int row = row0 + wm * 32 + i * 16 + quad * 4 + rr;
                float val = acc[i][j][rr] + bv;
                if (BF16OUT)
                    Cb[(size_t)row * N + col] = __float2bfloat16(val);
                else
                    Cf[(size_t)row * N + col] = val;
            }
        }
    }
}

// ---------------------------------------------------------------------------
// Batched q/k/v projections, 128x128 tile, BK=64 (32 MFMA/barrier).
// z=0: q scaled by temp/8*log2e; z=1: k; z=2: v written TRANSPOSED (vt)
// ---------------------------------------------------------------------------
__global__ __launch_bounds__(256) void gemm_qkv(
    const short* __restrict__ Aq, const short* __restrict__ Ak,
    const short* __restrict__ Av, const short* __restrict__ Wq,
    const short* __restrict__ Wk, const short* __restrict__ Wv,
    const float* __restrict__ bq, const float* __restrict__ bk,
    const float* __restrict__ bv, __hip_bfloat16* __restrict__ Cq,
    __hip_bfloat16* __restrict__ Ck, __hip_bfloat16* __restrict__ Cv,
    const float* __restrict__ tmp) {
    int z = blockIdx.z;
    const short* A = (z == 0) ? Aq : (z == 1) ? Ak : Av;
    const short* Wt = (z == 0) ? Wq : (z == 1) ? Wk : Wv;
    const float* bias = (z == 0) ? bq : (z == 1) ? bk : bv;

    __shared__ short As0[128][32], As1[128][32];
    __shared__ short Bs0[128][32], Bs1[128][32];
    int tid = threadIdx.x;
    int wave = tid >> 6, lane = tid & 63;
    int m16 = lane & 15, quad = lane >> 4;
    int wm = wave >> 1, wn = wave & 1;
    int row0 = blockIdx.y * 128, col0 = blockIdx.x * 128;
    int lr = lane >> 2;
    int kof = (lane & 3) * 8;

    float scale = 1.0f;
    if (z == 0)
        scale = tmp[(row0 >> 11) * HH + (col0 >> 6) + wn] * 0.125f * LOG2E;

    f32x4 acc[4][4];
#pragma unroll
    for (int i = 0; i < 4; ++i)
#pragma unroll
        for (int j = 0; j < 4; ++j) acc[i][j] = (f32x4){0.f, 0.f, 0.f, 0.f};

    for (int k0 = 0; k0 < CC; k0 += 64) {
#pragma unroll
        for (int j = 0; j < 2; ++j) {
            int rbase = wave * 32 + j * 16;
            const short* ar = A + (size_t)(row0 + rbase + lr) * CC + k0 + kof;
            async_copy16(ar, &As0[rbase][0]);
            async_copy16(ar + 32, &As1[rbase][0]);
            const short* br = Wt + (size_t)(col0 + rbase + lr) * CC + k0 + kof;
            async_copy16(br, &Bs0[rbase][0]);
            async_copy16(br + 32, &Bs1[rbase][0]);
        }
        __syncthreads();
#pragma unroll
        for (int kc = 0; kc < 2; ++kc) {
            short8 af[4], bfr[4];
#pragma unroll
            for (int i = 0; i < 4; ++i)
                af[i] = kc ? *(const short8*)&As1[wm * 64 + i * 16 + m16][quad * 8]
                           : *(const short8*)&As0[wm * 64 + i * 16 + m16][quad * 8];
#pragma unroll
            for (int j = 0; j < 4; ++j)
                bfr[j] = kc ? *(const short8*)&Bs1[wn * 64 + j * 16 + m16][quad * 8]
                            : *(const short8*)&Bs0[wn * 64 + j * 16 + m16][quad * 8];
#pragma unroll
            for (int i = 0; i < 4; ++i)
#pragma unroll
                for (int j = 0; j < 4; ++j)
                    acc[i][j] = __builtin_amdgcn_mfma_f32_16x16x32_bf16(
                        af[i], bfr[j], acc[i][j], 0, 0, 0);
        }
        __syncthreads();
    }
    if (z == 2) {
        int b = row0 >> 11;
        int t0r = (row0 & (TT - 1)) + wm * 64 + quad * 4;
#pragma unroll
        for (int i = 0; i < 4; ++i) {
#pragma unroll
            for (int j = 0; j < 4; ++j) {
                int col = col0 + wn * 64 + j * 16 + m16;
                int h = col >> 6, d = col & 63;
                float bv2 = bias[col];
                short4_t pk = pack_bf16x4(
                    acc[i][j][0] + bv2, acc[i][j][1] + bv2,
                    acc[i][j][2] + bv2, acc[i][j][3] + bv2);
                *(short4_t*)&Cv[(((size_t)(b * HH + h) * DD) + d) * TT + t0r +
                                i * 16] = pk;
            }
        }
    } else {
        __hip_bfloat16* C = (z == 0) ? Cq : Ck;
#pragma unroll
        for (int i = 0; i < 4; ++i) {
#pragma unroll
            for (int j = 0; j < 4; ++j) {
                int col = col0 + wn * 64 + j * 16 + m16;
                float bv2 = bias[col];
#pragma unroll
                for (int rr = 0; rr < 4; ++rr) {
                    int row = row0 + wm * 64 + i * 16 + quad * 4 + rr;
                    C[(size_t)row * CC + col] =
                        __float2bfloat16((acc[i][j][rr] + bv2) * scale);
                }
            }
        }
    }
}

// ---------------------------------------------------------------------------
// fused importance epilogue: LN(h1)+GELU -> dot w2 -> sigmoid -> xi = x*imp
// ---------------------------------------------------------------------------
__global__ __launch_bounds__(256) void imp_fused(
    const float* __restrict__ h1, const float* __restrict__ g,
    const float* __restrict__ beta, const float* __restrict__ w2,
    const float* __restrict__ b2, const float* __restrict__ x,
    __hip_bfloat16* __restrict__ xi) {
    int row = blockIdx.x;
    int tid = threadIdx.x;
    const float* hr = h1 + (size_t)row * CHALF;
    float v0 = hr[tid], v1 = hr[tid + 256];
    __shared__ float red[256];
    red[tid] = v0 + v1;
    __syncthreads();
#pragma unroll
    for (int o = 128; o > 0; o >>= 1) {
        if (tid < o) red[tid] += red[tid + o];
        __syncthreads();
    }
    float mean = red[0] * (1.0f / CHALF);
    __syncthreads();
    float d0 = v0 - mean, d1 = v1 - mean;
    red[tid] = d0 * d0 + d1 * d1;
    __syncthreads();
#pragma unroll
    for (int o = 128; o > 0; o >>= 1) {
        if (tid < o) red[tid] += red[tid + o];
        __syncthreads();
    }
    float inv = rsqrtf(red[0] * (1.0f / CHALF) + 1e-5f);
    __syncthreads();
    float ge0 = gelu_exact(d0 * inv * g[tid] + beta[tid]);
    float ge1 = gelu_exact(d1 * inv * g[tid + 256] + beta[tid + 256]);
    red[tid] = ge0 * w2[tid] + ge1 * w2[tid + 256];
    __syncthreads();
#pragma unroll
    for (int o = 128; o > 0; o >>= 1) {
        if (tid < o) red[tid] += red[tid + o];
        __syncthreads();
    }
    float z = red[0] + b2[0];
    float sg = 1.0f / (1.0f + expf(-z));
    float imp = fmaxf(sg, 1e-6f);
#pragma unroll
    for (int i = 0; i < 4; ++i) {
        int c = i * 256 + tid;
        xi[(size_t)row * CC + c] =
            __float2bfloat16(x[(size_t)row * CC + c] * imp);
    }
}

// ---------------------------------------------------------------------------
// LN + GELU, bf16 in -> bf16 out (vectorized short4 per thread)
// ---------------------------------------------------------------------------
__global__ __launch_bounds__(256) void ln_gelu_bb(
    const __hip_bfloat16* __restrict__ Y, const float* __restrict__ g,
    const float* __restrict__ beta, __hip_bfloat16* __restrict__ O) {
    int row = blockIdx.x;
    int tid = threadIdx.x;
    int c0 = tid * 4;
    short4_t raw = *(const short4_t*)&Y[(size_t)row * CC + c0];
    float v[4];
    float s = 0.f;
#pragma unroll
    for (int i = 0; i < 4; ++i) {
        v[i] = bf2f(raw[i]);
        s += v[i];
    }
    __shared__ float red[256];
    red[tid] = s;
    __syncthreads();
#pragma unroll
    for (int o = 128; o > 0; o >>= 1) {
        if (tid < o) red[tid] += red[tid + o];
        __syncthreads();
    }
    float mean = red[0] * (1.0f / CC);
    __syncthreads();
    s = 0.f;
#pragma unroll
    for (int i = 0; i < 4; ++i) {
        float d = v[i] - mean;
        s += d * d;
    }
    red[tid] = s;
    __syncthreads();
#pragma unroll
    for (int o = 128; o > 0; o >>= 1) {
        if (tid < o) red[tid] += red[tid + o];
        __syncthreads();
    }
    float inv = rsqrtf(red[0] * (1.0f / CC) + 1e-5f);
    float4 gg = *(const float4*)&g[c0];
    float4 bb = *(const float4*)&beta[c0];
    short4_t ov = pack_bf16x4(
        gelu_exact((v[0] - mean) * inv * gg.x + bb.x),
        gelu_exact((v[1] - mean) * inv * gg.y + bb.y),
        gelu_exact((v[2] - mean) * inv * gg.z + bb.z),
        gelu_exact((v[3] - mean) * inv * gg.w + bb.w));
    *(short4_t*)&O[(size_t)row * CC + c0] = ov;
}

// ---------------------------------------------------------------------------
// reasoned.mean(axis=1), stage 1 (partials over 128-row chunks)
// ---------------------------------------------------------------------------
__global__ __launch_bounds__(256) void mean_part(
    const __hip_bfloat16* __restrict__ R, float* __restrict__ part) {
    int idx = blockIdx.x * 256 + threadIdx.x;
    int c = idx & (CC - 1);
    int chunk = (idx >> 10) & 15;
    int b = idx >> 14;
    const __hip_bfloat16* base = R + ((size_t)(b * TT + chunk * 128)) * CC + c;
    float s = 0.f;
    for (int t = 0; t < 128; ++t) s += __bfloat162float(base[(size_t)t * CC]);
    part[idx] = s;
}

// ---------------------------------------------------------------------------
// temp_net stage 1 (+ fused mean finalize): acc1[b,col] = rm @ w1 + b1
// ---------------------------------------------------------------------------
__global__ __launch_bounds__(256) void temp_gemv1(
    const float* __restrict__ part, const float* __restrict__ w1,
    const float* __restrict__ b1, float* __restrict__ acc1) {
    __shared__ float rm_l[CC];
    __shared__ float red[256];
    int b = blockIdx.y;
    int c0 = blockIdx.x * 64;
    int tid = threadIdx.x;
    for (int cc = tid; cc < CC; cc += 256) {
        float s = 0.f;
#pragma unroll
        for (int ch = 0; ch < 16; ++ch)
            s += part[(size_t)(b * 16 + ch) * CC + cc];
        rm_l[cc] = s * (1.0f / TT);
    }
    __syncthreads();
    int col = c0 + (tid & 63);
    int kq = tid >> 6;  // 0..3
    float s = 0.f;
#pragma unroll 8
    for (int i = kq * 256; i < kq * 256 + 256; ++i)
        s = fmaf(rm_l[i], w1[(size_t)i * CHALF + col], s);
    red[tid] = s;
    __syncthreads();
    if (tid < 64) {
        float t = red[tid] + red[tid + 64] + red[tid + 128] + red[tid + 192];
        acc1[b * CHALF + tid + c0] = t + b1[col];
    }
}

// ---------------------------------------------------------------------------
// temp_net stage 2: LN(acc1) -> GELU -> @w2 + b2 -> softplus + 0.5
// ---------------------------------------------------------------------------
__global__ __launch_bounds__(512) void temp_fin(
    const float* __restrict__ acc1, const float* __restrict__ g,
    const float* __restrict__ beta, const float* __restrict__ w2,
    const float* __restrict__ b2, float* __restrict__ temp) {
    __shared__ float red[512];
    __shared__ float wred[8][16];
    int b = blockIdx.x;
    int tid = threadIdx.x;
    int wave = tid >> 6, lane = tid & 63;
    float acc = acc1[b * CHALF + tid];
    red[tid] = acc;
    __syncthreads();
#pragma unroll
    for (int o = 256; o > 0; o >>= 1) {
        if (tid < o) red[tid] += red[tid + o];
        __syncthreads();
    }
    float mean = red[0] * (1.0f / CHALF);
    __syncthreads();
    float d = acc - mean;
    red[tid] = d * d;
    __syncthreads();
#pragma unroll
    for (int o = 256; o > 0; o >>= 1) {
        if (tid < o) red[tid] += red[tid + o];
        __syncthreads();
    }
    float inv = rsqrtf(red[0] * (1.0f / CHALF) + 1e-5f);
    float ht = gelu_exact((acc - mean) * inv * g[tid] + beta[tid]);
    float p[16];
#pragma unroll
    for (int j = 0; j < 16; ++j) p[j] = ht * w2[tid * HH + j];
#pragma unroll
    for (int off = 1; off < 64; off <<= 1)
#pragma unroll
        for (int j = 0; j < 16; ++j) p[j] += __shfl_xor(p[j], off, 64);
    if (lane == 0)
#pragma unroll
        for (int j = 0; j < 16; ++j) wred[wave][j] = p[j];
    __syncthreads();
    if (tid < HH) {
        float s = b2[tid];
#pragma unroll
        for (int w = 0; w < 8; ++w) s += wred[w][tid];
        float sp = fmaxf(s, 0.f) + log1pf(expf(-fabsf(s)));
        temp[b * HH + tid] = sp + 0.5f;
    }
}

// ---------------------------------------------------------------------------
// MFMA flash attention (measured-best): 128-row q-tile, transposed-QK softmax,
// O^T PV (per-lane alpha/l), ballot-gated rescale, raw v_exp_f32.
// ---------------------------------------------------------------------------
__global__ __launch_bounds__(256) void flash_attn_mfma(
    const short* __restrict__ q, const short* __restrict__ k,
    const short* __restrict__ vt, const int* __restrict__ mask,
    const int* __restrict__ flags, __hip_bfloat16* __restrict__ out) {
    __shared__ short Ks[64][72];    // [key][d]
    __shared__ short Vt[64][72];    // [d][key]
    __shared__ short Ps[128][72];   // [q-row][key], wave-private strips
    int tid = threadIdx.x;
    int wave = tid >> 6, lane = tid & 63;
    int m16 = lane & 15, quad = lane >> 4;
    int qt = blockIdx.x;            // 128-row q tile
    int q0 = qt * 128;
    int bh = blockIdx.y;
    int b = bh >> 4, h = bh & 15;

    short8 qf[2][2];
#pragma unroll
    for (int qg = 0; qg < 2; ++qg) {
        const short* qrow = q + ((size_t)(b * TT + q0 + wave * 32 + qg * 16 + m16)) * CC +
                            h * DD + quad * 8;
        qf[qg][0] = *(const short8*)(qrow);
        qf[qg][1] = *(const short8*)(qrow + 32);
    }

    float m_run[2] = {-INFINITY, -INFINITY};
    float l_run[2] = {0.f, 0.f};
    f32x4 acc_o[2][4];
#pragma unroll
    for (int qg = 0; qg < 2; ++qg)
#pragma unroll
        for (int t = 0; t < 4; ++t) acc_o[qg][t] = (f32x4){0.f, 0.f, 0.f, 0.f};

    for (int kt = 0; kt < TT / 64; ++kt) {
        int kb = kt * 64;
#pragma unroll
        for (int i = 0; i < 2; ++i) {
            int idx = i * 256 + tid;
            int r = idx >> 3;
            int dc = (idx & 7) * 8;
            *(short8*)&Ks[r][dc] =
                *(const short8*)(k + ((size_t)(b * TT + kb + r)) * CC + h * DD + dc);
            *(short8*)&Vt[r][dc] =
                *(const short8*)(vt + ((size_t)bh * DD + r) * TT + kb + dc);
        }
        __syncthreads();

        short8 kf[4][2];
#pragma unroll
        for (int t = 0; t < 4; ++t) {
            kf[t][0] = *(const short8*)&Ks[t * 16 + m16][quad * 8];
            kf[t][1] = *(const short8*)&Ks[t * 16 + m16][32 + quad * 8];
        }
        int fl = flags[(b * 32 + 2 * qt + (wave >> 1)) * 32 + kt];

#pragma unroll
        for (int qg = 0; qg < 2; ++qg) {
            f32x4 sacc[4];
#pragma unroll
            for (int t = 0; t < 4; ++t) sacc[t] = (f32x4){0.f, 0.f, 0.f, 0.f};
#pragma unroll
            for (int t = 0; t < 4; ++t) {
                sacc[t] = __builtin_amdgcn_mfma_f32_16x16x32_bf16(kf[t][0], qf[qg][0], sacc[t], 0, 0, 0);
                sacc[t] = __builtin_amdgcn_mfma_f32_16x16x32_bf16(kf[t][1], qf[qg][1], sacc[t], 0, 0, 0);
            }
            float sv[4][4];
#pragma unroll
            for (int t = 0; t < 4; ++t)
#pragma unroll
                for (int r = 0; r < 4; ++r) sv[t][r] = sacc[t][r];
            if (fl == 0) {
                int qrow = q0 + wave * 32 + qg * 16 + m16;
#pragma unroll
                for (int t = 0; t < 4; ++t)
#pragma unroll
                    for (int r = 0; r < 4; ++r) {
                        int kg = kb + t * 16 + quad * 4 + r;
                        if (mask[((size_t)(b * TT + qrow)) * TT + kg] == 0)
                            sv[t][r] = -INFINITY;
                    }
            }
            float mx = sv[0][0];
#pragma unroll
            for (int t = 0; t < 4; ++t)
#pragma unroll
                for (int r = 0; r < 4; ++r) mx = fmaxf(mx, sv[t][r]);
            mx = fmaxf(mx, __shfl_xor(mx, 16, 64));
            mx = fmaxf(mx, __shfl_xor(mx, 32, 64));
            float mnew = fmaxf(m_run[qg], mx);
            if (__any(mnew > m_run[qg])) {
                float alpha = __builtin_amdgcn_exp2f(m_run[qg] - mnew);
                l_run[qg] *= alpha;
#pragma unroll
                for (int td = 0; td < 4; ++td)
#pragma unroll
                    for (int r = 0; r < 4; ++r) acc_o[qg][td][r] *= alpha;
            }
            m_run[qg] = mnew;
            int prow = wave * 32 + qg * 16 + m16;
            float psum = 0.f;
#pragma unroll
            for (int t = 0; t < 4; ++t) {
                short4_t pk;
#pragma unroll
                for (int r = 0; r < 4; ++r) {
                    float p = __builtin_amdgcn_exp2f(sv[t][r] - mnew);
                    psum += p;
                    pk[r] = f2bf(p);
                }
                *(short4_t*)&Ps[prow][t * 16 + quad * 4] = pk;
            }
            psum += __shfl_xor(psum, 16, 64);
            psum += __shfl_xor(psum, 32, 64);
            l_run[qg] += psum;
        }

        // PV as O^T = V^T P^T
#pragma unroll
        for (int kc = 0; kc < 2; ++kc) {
            short8 vf[4];
#pragma unroll
            for (int td = 0; td < 4; ++td)
                vf[td] = *(const short8*)&Vt[td * 16 + m16][kc * 32 + quad * 8];
#pragma unroll
            for (int qg = 0; qg < 2; ++qg) {
                short8 pf = *(const short8*)&Ps[wave * 32 + qg * 16 + m16][kc * 32 + quad * 8];
#pragma unroll
                for (int td = 0; td < 4; ++td)
                    acc_o[qg][td] = __builtin_amdgcn_mfma_f32_16x16x32_bf16(
                        vf[td], pf, acc_o[qg][td], 0, 0, 0);
            }
        }
        __syncthreads();
    }

#pragma unroll
    for (int qg = 0; qg < 2; ++qg) {
        float inv = 1.0f / l_run[qg];
        int row = b * TT + q0 + wave * 32 + qg * 16 + m16;
#pragma unroll
        for (int td = 0; td < 4; ++td) {
            short4_t pk = pack_bf16x4(
                acc_o[qg][td][0] * inv, acc_o[qg][td][1] * inv,
                acc_o[qg][td][2] * inv, acc_o[qg][td][3] * inv);
            *(short4_t*)&out[(size_t)row * CC + h * DD + td * 16 + quad * 4] = pk;
        }
    }
}

// ---------------------------------------------------------------------------
// Final: out = LN(x + proj), proj in bf16 (vectorized 4/thread)
// ---------------------------------------------------------------------------
__global__ __launch_bounds__(256) void final_ln_b(
    const float* __restrict__ x, const __hip_bfloat16* __restrict__ p,
    const float* __restrict__ g, const float* __restrict__ beta,
    float* __restrict__ out) {
    int row = blockIdx.x;
    int tid = threadIdx.x;
    int c0 = tid * 4;
    float4 xv = *(const float4*)&x[(size_t)row * CC + c0];
    short4_t pv = *(const short4_t*)&p[(size_t)row * CC + c0];
    float v[4] = {xv.x + bf2f(pv[0]), xv.y + bf2f(pv[1]),
                  xv.z + bf2f(pv[2]), xv.w + bf2f(pv[3])};
    float s = v[0] + v[1] + v[2] + v[3];
    __shared__ float red[256];
    red[tid] = s;
    __syncthreads();
#pragma unroll
    for (int o = 128; o > 0; o >>= 1) {
        if (tid < o) red[tid] += red[tid + o];
        __syncthreads();
    }
    float mean = red[0] * (1.0f / CC);
    __syncthreads();
    s = 0.f;
#pragma unroll
    for (int i = 0; i < 4; ++i) {
        float d = v[i] - mean;
        s += d * d;
    }
    red[tid] = s;
    __syncthreads();
#pragma unroll
    for (int o = 128; o > 0; o >>= 1) {
        if (tid < o) red[tid] += red[tid + o];
        __syncthreads();
    }
    float inv = rsqrtf(red[0] * (1.0f / CC) + 1e-5f);
    float4 gg = *(const float4*)&g[c0];
    float4 bb = *(const float4*)&beta[c0];
    float4 ov = {(v[0] - mean) * inv * gg.x + bb.x,
                 (v[1] - mean) * inv * gg.y + bb.y,
                 (v[2] - mean) * inv * gg.z + bb.z,
                 (v[3] - mean) * inv * gg.w + bb.w};
    *(float4*)&out[(size_t)row * CC + c0] = ov;
}

extern "C" void kernel_launch(void* const* d_in, const int* in_sizes, int n_in,
                              void* d_out, int out_size, void* d_ws,
                              size_t ws_size, hipStream_t stream) {
    const float* x        = (const float*)d_in[0];
    const int*   mask     = (const int*)d_in[1];
    const float* imp_w1   = (const float*)d_in[2];
    const float* imp_b1   = (const float*)d_in[3];
    const float* imp_g    = (const float*)d_in[4];
    const float* imp_beta = (const float*)d_in[5];
    const float* imp_w2   = (const float*)d_in[6];
    const float* imp_b2   = (const float*)d_in[7];
    const float* rsn_w1   = (const float*)d_in[8];
    const float* rsn_b1   = (const float*)d_in[9];
    const float* rsn_g    = (const float*)d_in[10];
    const float* rsn_beta = (const float*)d_in[11];
    const float* rsn_w2   = (const float*)d_in[12];
    const float* rsn_b2   = (const float*)d_in[13];
    const float* q_w      = (const float*)d_in[14];
    const float* q_b      = (const float*)d_in[15];
    const float* k_w      = (const float*)d_in[16];
    const float* k_b      = (const float*)d_in[17];
    const float* v_w      = (const float*)d_in[18];
    const float* v_b      = (const float*)d_in[19];
    const float* o_w      = (const float*)d_in[20];
    const float* o_b      = (const float*)d_in[21];
    const float* tmp_w1   = (const float*)d_in[22];
    const float* tmp_b1   = (const float*)d_in[23];
    const float* tmp_g    = (const float*)d_in[24];
    const float* tmp_beta = (const float*)d_in[25];
    const float* tmp_w2   = (const float*)d_in[26];
    const float* tmp_b2   = (const float*)d_in[27];
    const float* norm_g   = (const float*)d_in[28];
    const float* norm_b   = (const float*)d_in[29];
    float* out = (float*)d_out;
    float* ws  = (float*)d_ws;

    // workspace layout (float offsets)
    float* h1  = ws;                       // [4096,512] fp32
    __hip_bfloat16* g1b   = (__hip_bfloat16*)(ws + 2097152);   // rsn1 out bf16 (later o-proj out)
    __hip_bfloat16* x_bf  = (__hip_bfloat16*)(ws + 6291456);
    __hip_bfloat16* xi_bf = (__hip_bfloat16*)(ws + 8388608);
    __hip_bfloat16* h2b   = (__hip_bfloat16*)(ws + 10485760);  // LN(rsn1) out
    __hip_bfloat16* rs_bf = (__hip_bfloat16*)(ws + 12582912);  // reasoned, later attn out
    __hip_bfloat16* qb    = (__hip_bfloat16*)(ws + 14680064);
    __hip_bfloat16* kb    = (__hip_bfloat16*)(ws + 16777216);
    __hip_bfloat16* vtb   = (__hip_bfloat16*)(ws + 20971520);  // [32,64,2048]
    __hip_bfloat16* imp_w1t = (__hip_bfloat16*)(ws + 23068672);  // [512,1024]
    __hip_bfloat16* rsn_w1t = (__hip_bfloat16*)(ws + 23330816);  // [1024,1024]
    __hip_bfloat16* rsn_w2t = (__hip_bfloat16*)(ws + 23855104);
    __hip_bfloat16* q_wt    = (__hip_bfloat16*)(ws + 24379392);
    __hip_bfloat16* k_wt    = (__hip_bfloat16*)(ws + 24903680);
    __hip_bfloat16* v_wt    = (__hip_bfloat16*)(ws + 25427968);
    __hip_bfloat16* o_wt    = (__hip_bfloat16*)(ws + 25952256);
    float* tmp  = ws + 26478592;   // [2,16]
    float* part = ws + 26479104;   // [2,16,1024]
    int*   flg  = (int*)(ws + 26511872);  // [2,32,32]
    float* acc1 = ws + 26513920;   // [2,512]

    dim3 blk(256);
    // fused prep: x->bf16, mask flags, 7 weight transposes
    prep<<<5760, blk, 0, stream>>>(
        x, x_bf, mask, flg,
        imp_w1, rsn_w1, rsn_w2, q_w, k_w, v_w, o_w,
        imp_w1t, rsn_w1t, rsn_w2t, q_wt, k_wt, v_wt, o_wt);

    // importance net (GEMM + fused LN/GELU/gate)
    gemm_mfma64<false><<<dim3(CHALF / 128, NN / 64), blk, 0, stream>>>(
        (const short*)x_bf, (const short*)imp_w1t, imp_b1, h1, nullptr, NN, CHALF, CC);
    imp_fused<<<NN, blk, 0, stream>>>(h1, imp_g, imp_beta, imp_w2, imp_b2, x, xi_bf);
    // reasoning net (bf16 intermediates)
    gemm_mfma64<true><<<dim3(CC / 128, NN / 64), blk, 0, stream>>>(
        (const short*)xi_bf, (const short*)rsn_w1t, rsn_b1, nullptr, g1b, NN, CC, CC);
    ln_gelu_bb<<<NN, blk, 0, stream>>>(g1b, rsn_g, rsn_beta, h2b);
    gemm_mfma64<true><<<dim3(CC / 128, NN / 64), blk, 0, stream>>>(
        (const short*)h2b, (const short*)rsn_w2t, rsn_b2, nullptr, rs_bf, NN, CC, CC);
    // temperature net
    mean_part<<<128, blk, 0, stream>>>(rs_bf, part);
    temp_gemv1<<<dim3(CHALF / 64, BB), blk, 0, stream>>>(part, tmp_w1, tmp_b1, acc1);
    temp_fin<<<BB, dim3(512), 0, stream>>>(acc1, tmp_g, tmp_beta, tmp_w2, tmp_b2, tmp);
    // q/k/v projections batched, BK=64; q scaled by temp/8*log2e; v transposed
    gemm_qkv<<<dim3(CC / 128, NN / 128, 3), blk, 0, stream>>>(
        (const short*)rs_bf, (const short*)xi_bf, (const short*)x_bf,
        (const short*)q_wt, (const short*)k_wt, (const short*)v_wt,
        q_b, k_b, v_b, qb, kb, vtb, tmp);
    // flash attention (measured-best config)
    flash_attn_mfma<<<dim3(TT / 128, BB * HH), blk, 0, stream>>>(
        (const short*)qb, (const short*)kb, (const short*)vtb, mask, flg, rs_bf);
    // output projection (bf16 out into g1b, free now) + residual LN
    gemm_mfma64<true><<<dim3(CC / 128, NN / 64), blk, 0, stream>>>(
        (const short*)rs_bf, (const short*)o_wt, o_b, nullptr, g1b, NN, CC, CC);
    final_ln_b<<<NN, blk, 0, stream>>>(x, g1b, norm_g, norm_b, out);
}